// Round 1
// 1005.630 us; speedup vs baseline: 1.0126x; 1.0126x over previous
//
#include <hip/hip_runtime.h>
#include <cstddef>

#define BB 16
#define NK 2048
#define TK 4096
#define HH 256
#define H2 512

// ---------------- dec_fea = s_t_hat @ dec_proj_w + b  (16x256, tiny) --------
// K-split x8 for parallelism (128 blocks instead of 16); partials via atomicAdd
// into a zeroed dec_fea; bias folded into the ks==0 block.
__global__ void k_dec_fea(const float* __restrict__ s_t_hat,
                          const float* __restrict__ Wd,
                          const float* __restrict__ bd,
                          float* __restrict__ dec_fea) {
    int b = blockIdx.x, ks = blockIdx.y;   // ks in [0,8)
    int d = threadIdx.x;
    __shared__ float s[64];
    if (d < 64) s[d] = s_t_hat[b * H2 + ks * 64 + d];
    __syncthreads();
    float acc = (ks == 0) ? bd[d] : 0.f;
    #pragma unroll
    for (int j = 0; j < 64; ++j)
        acc = fmaf(s[j], Wd[(ks * 64 + j) * HH + d], acc);
    atomicAdd(&dec_fea[b * HH + d], acc);
}

// ---------------- scores[b,k] = tanh(enc[b,k,:]@W + dec[b,:]) . v -----------
// Register-tiled: block = 32 nodes x 256 d (halves W L2 re-read vs 16 nodes).
// Thread (lane=d-quad, wave=node-octet) holds acc[8 nodes][4 d]. LDS enc reads
// are wave-broadcast, amortized over 16 FMA each.
__global__ __launch_bounds__(256) void k_scores(const float* __restrict__ enc,
                         const float* __restrict__ Wenc,
                         const float* __restrict__ dec_fea,
                         const float* __restrict__ v,
                         float* __restrict__ scores) {
    int b   = blockIdx.y;
    int k0  = blockIdx.x * 32;
    int tid = threadIdx.x;
    int lane = tid & 63;   // d-quad index: d = lane*4 .. +3
    int wv   = tid >> 6;   // node group: nodes wv*8 .. +7

    __shared__ float4 encSV[32 * 64];   // 32 nodes x 64 float4 = 32 KB
    const float4* baseV = (const float4*)(enc + ((size_t)b * NK + k0) * HH);
    #pragma unroll
    for (int r = 0; r < 8; ++r) encSV[r * 256 + tid] = baseV[r * 256 + tid];
    __syncthreads();

    const float4* Wv = (const float4*)Wenc;  // (256 h) x (64 d-quads)
    float4 acc[8];
    #pragma unroll
    for (int i = 0; i < 8; ++i) acc[i] = make_float4(0.f, 0.f, 0.f, 0.f);

    for (int h4 = 0; h4 < 64; ++h4) {
        float4 w0 = Wv[(h4 * 4 + 0) * 64 + lane];
        float4 w1 = Wv[(h4 * 4 + 1) * 64 + lane];
        float4 w2 = Wv[(h4 * 4 + 2) * 64 + lane];
        float4 w3 = Wv[(h4 * 4 + 3) * 64 + lane];
        #pragma unroll
        for (int i = 0; i < 8; ++i) {
            float4 e = encSV[(wv * 8 + i) * 64 + h4];  // broadcast
            acc[i].x = fmaf(e.x, w0.x, acc[i].x); acc[i].y = fmaf(e.x, w0.y, acc[i].y);
            acc[i].z = fmaf(e.x, w0.z, acc[i].z); acc[i].w = fmaf(e.x, w0.w, acc[i].w);
            acc[i].x = fmaf(e.y, w1.x, acc[i].x); acc[i].y = fmaf(e.y, w1.y, acc[i].y);
            acc[i].z = fmaf(e.y, w1.z, acc[i].z); acc[i].w = fmaf(e.y, w1.w, acc[i].w);
            acc[i].x = fmaf(e.z, w2.x, acc[i].x); acc[i].y = fmaf(e.z, w2.y, acc[i].y);
            acc[i].z = fmaf(e.z, w2.z, acc[i].z); acc[i].w = fmaf(e.z, w2.w, acc[i].w);
            acc[i].x = fmaf(e.w, w3.x, acc[i].x); acc[i].y = fmaf(e.w, w3.y, acc[i].y);
            acc[i].z = fmaf(e.w, w3.z, acc[i].z); acc[i].w = fmaf(e.w, w3.w, acc[i].w);
        }
    }

    float4 df = ((const float4*)(dec_fea + b * HH))[lane];
    float4 vv = ((const float4*)v)[lane];
    #pragma unroll
    for (int i = 0; i < 8; ++i) {
        float p = tanhf(acc[i].x + df.x) * vv.x
                + tanhf(acc[i].y + df.y) * vv.y
                + tanhf(acc[i].z + df.z) * vv.z
                + tanhf(acc[i].w + df.w) * vv.w;
        #pragma unroll
        for (int off = 32; off > 0; off >>= 1) p += __shfl_down(p, off, 64);
        if (lane == 0) scores[b * NK + k0 + wv * 8 + i] = p;
    }
}

// ---------------- masked softmax + renorm (max-shift cancels in renorm) -----
__global__ void k_softmax(const float* __restrict__ scores,
                          const float* __restrict__ mask,
                          float* __restrict__ attn) {
    int b = blockIdx.x, tid = threadIdx.x;
    int lane = tid & 63, wv = tid >> 6;
    __shared__ float redmax[4], redsum[4];
    float vals[8];
    float m = -1e30f;
    #pragma unroll
    for (int r = 0; r < 8; ++r) {
        vals[r] = scores[b * NK + r * 256 + tid];
        m = fmaxf(m, vals[r]);
    }
    #pragma unroll
    for (int off = 1; off < 64; off <<= 1) m = fmaxf(m, __shfl_xor(m, off, 64));
    if (lane == 0) redmax[wv] = m;
    __syncthreads();
    m = fmaxf(fmaxf(redmax[0], redmax[1]), fmaxf(redmax[2], redmax[3]));
    float s = 0.f;
    #pragma unroll
    for (int r = 0; r < 8; ++r) {
        float e = __expf(vals[r] - m) * mask[b * NK + r * 256 + tid];
        vals[r] = e;
        s += e;
    }
    #pragma unroll
    for (int off = 1; off < 64; off <<= 1) s += __shfl_xor(s, off, 64);
    if (lane == 0) redsum[wv] = s;
    __syncthreads();
    s = redsum[0] + redsum[1] + redsum[2] + redsum[3];
    float inv = 1.f / s;
    #pragma unroll
    for (int r = 0; r < 8; ++r) attn[b * NK + r * 256 + tid] = vals[r] * inv;
}

// ---------------- c_t = attn . enc  (k-split, atomic accumulate) ------------
__global__ void k_ct(const float* __restrict__ attn,
                     const float* __restrict__ enc,
                     float* __restrict__ out) {
    int b = blockIdx.y;
    int k0 = blockIdx.x * 64;
    int h = threadIdx.x;
    const float* e  = enc + ((size_t)b * NK + k0) * HH;
    const float* wb = attn + b * NK + k0;
    float acc = 0.f;
    #pragma unroll 8
    for (int k = 0; k < 64; ++k) acc = fmaf(wb[k], e[(size_t)k * HH + h], acc);
    atomicAdd(&out[b * HH + h], acc);
}

// ---------------- streamed w(b,k) x M(b,k,NCOLS) -> out(b,NCOLS) ------------
// KCH-way k-split for occupancy; attn chunk staged in LDS (broadcast reads,
// no per-iteration scalar-load dependency in the stream loop).
template <int NCOLS, int KCH>
__global__ __launch_bounds__(256) void k_vecmat(const float* __restrict__ w,
                         const float* __restrict__ M,
                         float* __restrict__ out) {
    constexpr int KR = NK / KCH;
    int b  = blockIdx.z;
    int k0 = blockIdx.y * KR;
    int t  = blockIdx.x * 1024 + threadIdx.x * 4;
    __shared__ float sw[KR];
    for (int i = threadIdx.x; i < KR; i += 256) sw[i] = w[b * NK + k0 + i];
    __syncthreads();
    const float4* Mv = (const float4*)(M + (size_t)b * NK * NCOLS
                                         + (size_t)k0 * NCOLS) + (t >> 2);
    float4 acc = make_float4(0.f, 0.f, 0.f, 0.f);
    #pragma unroll 8
    for (int k = 0; k < KR; ++k) {
        float a = sw[k];
        float4 vv = Mv[(size_t)k * (NCOLS / 4)];
        acc.x = fmaf(a, vv.x, acc.x);
        acc.y = fmaf(a, vv.y, acc.y);
        acc.z = fmaf(a, vv.z, acc.z);
        acc.w = fmaf(a, vv.w, acc.w);
    }
    float* o = out + b * NCOLS + t;
    atomicAdd(o + 0, acc.x);
    atomicAdd(o + 1, acc.y);
    atomicAdd(o + 2, acc.z);
    atomicAdd(o + 3, acc.w);
}

// ---------------- flow_out = (attn + one_hop + two_hop) * 0.33333 -----------
__global__ void k_flowout(const float* __restrict__ attn,
                          const float* __restrict__ oh,
                          const float* __restrict__ th,
                          float* __restrict__ out) {
    int i = blockIdx.x * 256 + threadIdx.x;
    out[i] = (attn[i] + oh[i] + th[i]) * 0.33333f;
}

// ---------------- tok normalize ---------------------------------------------
__global__ void k_toknorm(const float* __restrict__ tok_raw,
                          float* __restrict__ out) {
    int b = blockIdx.x, tid = threadIdx.x;
    int lane = tid & 63, wv = tid >> 6;
    __shared__ float redsum[4];
    float vals[16];
    float s = 0.f;
    #pragma unroll
    for (int r = 0; r < 16; ++r) {
        vals[r] = tok_raw[b * TK + r * 256 + tid];
        s += vals[r];
    }
    #pragma unroll
    for (int off = 1; off < 64; off <<= 1) s += __shfl_xor(s, off, 64);
    if (lane == 0) redsum[wv] = s;
    __syncthreads();
    s = redsum[0] + redsum[1] + redsum[2] + redsum[3];
    float inv = 1.f / s;
    #pragma unroll
    for (int r = 0; r < 16; ++r) out[b * TK + r * 256 + tid] = vals[r] * inv;
}

extern "C" void kernel_launch(void* const* d_in, const int* in_sizes, int n_in,
                              void* d_out, int out_size, void* d_ws, size_t ws_size,
                              hipStream_t stream) {
    const float* s_t_hat = (const float*)d_in[0];
    const float* enc     = (const float*)d_in[1];
    const float* n2t     = (const float*)d_in[2];
    const float* mask    = (const float*)d_in[3];
    const float* graph   = (const float*)d_in[4];
    // d_in[5] flow, d_in[6] W_c_w: dead code in reference
    const float* Wenc    = (const float*)d_in[7];
    const float* Wdec    = (const float*)d_in[8];
    const float* bdec    = (const float*)d_in[9];
    const float* vnode   = (const float*)d_in[10];

    float* out = (float*)d_out;
    float* ws  = (float*)d_ws;

    // workspace layout (floats)
    float* dec_fea = ws;            //  4096
    float* scores  = ws + 4096;     // 32768
    float* tok_raw = ws + 36864;    // 65536
    float* one_hop = ws + 102400;   // 32768
    float* two_hop = ws + 135168;   // 32768  (total 167936 floats = 656 KiB)

    // output layout (return order): c_t, attn, tok, flow_out
    float* c_t   = out;             //  4096
    float* attn  = out + 4096;      // 32768
    float* tok   = out + 36864;     // 65536
    float* flowo = out + 102400;    // 32768

    // zero the atomic-accumulation buffers (harness poisons d_out/d_ws)
    hipMemsetAsync(dec_fea, 0, 4096 * sizeof(float), stream);
    hipMemsetAsync(c_t, 0, 4096 * sizeof(float), stream);
    hipMemsetAsync(tok_raw, 0, (65536 + 32768 + 32768) * sizeof(float), stream);

    k_dec_fea<<<dim3(BB, 8), 256, 0, stream>>>(s_t_hat, Wdec, bdec, dec_fea);
    k_scores<<<dim3(NK / 32, BB), 256, 0, stream>>>(enc, Wenc, dec_fea, vnode, scores);
    k_softmax<<<BB, 256, 0, stream>>>(scores, mask, attn);
    // c_t right after scores so enc (32 MB) is still L3-hot
    k_ct<<<dim3(32, BB), 256, 0, stream>>>(attn, enc, c_t);
    // both graph passes adjacent for L3 reuse of the 256 MB graph
    k_vecmat<NK, 32><<<dim3(2, 32, BB), 256, 0, stream>>>(attn, graph, one_hop);
    k_vecmat<NK, 32><<<dim3(2, 32, BB), 256, 0, stream>>>(one_hop, graph, two_hop);
    // flowout while one_hop/two_hop are L2-hot
    k_flowout<<<(BB * NK) / 256, 256, 0, stream>>>(attn, one_hop, two_hop, flowo);
    // big 512 MB node_to_token stream last
    k_vecmat<TK, 16><<<dim3(4, 16, BB), 256, 0, stream>>>(attn, n2t, tok_raw);
    k_toknorm<<<BB, 256, 0, stream>>>(tok_raw, tok);
}